// Round 11
// baseline (295.708 us; speedup 1.0000x reference)
//
#include <hip/hip_runtime.h>
#include <math.h>

typedef unsigned short u16;
typedef unsigned int   u32;
using short8  = __attribute__((ext_vector_type(8))) short;
using float4v = __attribute__((ext_vector_type(4))) float;

__device__ __forceinline__ float b2f(u16 u){ return __uint_as_float(((u32)u)<<16); }
__device__ __forceinline__ u16 f2b(float f){
  u32 x = __float_as_uint(f);
  x += 0x7FFFu + ((x>>16)&1u);   // RNE; inputs are tame (no NaN)
  return (u16)(x>>16);
}

// hardware packed f32->bf16 (RNE), 1 instr for 2 values
__device__ __forceinline__ u32 cvtpk_bf16(float lo, float hi){
  u32 r; asm("v_cvt_pk_bf16_f32 %0, %1, %2" : "=v"(r) : "v"(lo), "v"(hi));
  return r;
}

// async global->LDS, 16B per lane. LDS dest = wave-uniform base + lane*16.
__device__ __forceinline__ void gload_lds16(const u16* g, u16* l){
  __builtin_amdgcn_global_load_lds((const __attribute__((address_space(1))) void*)g,
                                   (__attribute__((address_space(3))) void*)l, 16, 0, 0);
}

// tanh-form GELU in sigmoid shape: x * rcp(1 + exp2(x*fma(c2,x^2,c1)))
// 7 VALU instrs (2 transcendental), no fp32 divide. |err vs exact erf-GELU| <~3e-3.
__device__ __forceinline__ float gelu_t(float x){
  float x2 = x*x;
  float z  = x * __builtin_fmaf(-0.1029434f, x2, -2.3022077f);
  float e  = __builtin_amdgcn_exp2f(z);
  return x * __builtin_amdgcn_rcpf(1.f + e);
}

// ------- weight prep: wqkvT/woT transposed; w1P/w2P packed in MFMA A-fragment order -------
__global__ void transpose_all(const float* __restrict__ wqkv, const float* __restrict__ wo,
                              const float* __restrict__ w1,   const float* __restrict__ w2,
                              u16* __restrict__ wqkvT, u16* __restrict__ woT,
                              u16* __restrict__ w1P,   u16* __restrict__ w2P){
  int idx = blockIdx.x*256 + threadIdx.x;
  if (idx < 110592){ int r=idx/576, c=idx-r*576; wqkvT[c*192+r]=f2b(wqkv[idx]); }
  else if (idx < 147456){ int j=idx-110592; int r=j/192, c=j-r*192; woT[c*192+r]=f2b(wo[j]); }
  else if (idx < 294912){
    int j = idx-147456;
    int tile = j >> 9, w = j & 511;            // tile = hct*6+ks
    int e = w & 7, l16 = (w>>3)&15, quad = w>>7;
    int hc = (tile/6)*16 + l16, k = (tile%6)*32 + quad*8 + e;
    w1P[j] = f2b(w1[k*768 + hc]);
  } else if (idx < 442368){
    int j = idx-294912;
    int tile = j >> 9, w = j & 511;            // tile = oct*24+kk
    int e = w & 7, l16 = (w>>3)&15, quad = w>>7;
    int oc = (tile/24)*16 + l16, k = (tile%24)*32 + quad*8 + e;
    w2P[j] = f2b(w2[k*192 + oc]);
  }
}

// ---------------- LayerNorm1 (fp32 in, bf16 out) + roll(-2) + window partition ----------------
__global__ __launch_bounds__(256) void ln_kernel(const float* __restrict__ x,
    const float* __restrict__ g, const float* __restrict__ bvec,
    u16* __restrict__ out)
{
  int wave = threadIdx.x >> 6, lane = threadIdx.x & 63;
  int token = blockIdx.x*4 + wave;          // enumerates SHIFTED coords
  int b = token >> 15, r = token & 32767;
  int hs = r >> 10, ws = (r >> 5) & 31, ds = r & 31;
  int h = (hs+2)&31, w = (ws+2)&31, d = (ds+2)&31;
  int src = ((b*32 + h)*32 + w)*32 + d;
  int win = ((b*8 + (hs>>2))*8 + (ws>>2))*8 + (ds>>2);
  int n   = ((hs&3)*4 + (ws&3))*4 + (ds&3);
  int dst = win*64 + n;
  float v[3];
  #pragma unroll
  for (int t=0;t<3;t++) v[t] = x[(size_t)src*192 + lane + t*64];
  float s  = v[0]+v[1]+v[2];
  float s2 = v[0]*v[0]+v[1]*v[1]+v[2]*v[2];
  #pragma unroll
  for (int o=32;o>=1;o>>=1){ s += __shfl_xor(s,o); s2 += __shfl_xor(s2,o); }
  float mean = s*(1.0f/192.0f);
  float var  = s2*(1.0f/192.0f) - mean*mean;
  float rstd = rsqrtf(var + 1e-5f);
  #pragma unroll
  for (int t=0;t<3;t++){
    int c = lane + t*64;
    out[(size_t)dst*192 + c] = f2b((v[t]-mean)*rstd*g[c] + bvec[c]);
  }
}

// ---------------- MFMA GEMM, full-K-chunk, XCD-swizzled grid (round-1 form) ----------------
template<int MODE, int NB>
__global__ __launch_bounds__(256) void gemm_fk(
    const u16* __restrict__ A, const u16* __restrict__ BT, const float* __restrict__ bias,
    const int K, const int N,
    u16* __restrict__ outb, float* __restrict__ outf, const float* __restrict__ resf)
{
  __shared__ u16 As[64*192];
  __shared__ u16 Bs[64*192];
  const int lin = blockIdx.x;
  const int xcd = lin & 7, idx = lin >> 3;
  const int mb = idx / NB, nb = idx - mb*NB;
  const int m0 = (xcd*128 + mb) * 64, n0 = nb * 64;
  const int tid = threadIdx.x;
  const int wv = tid >> 6, lane = tid & 63;
  const int quad = lane >> 4, l16 = lane & 15;
  const int wm = (wv >> 1) * 32, wn = (wv & 1) * 32;

  float4v acc[2][2];
  #pragma unroll
  for (int a=0;a<2;a++) for (int b=0;b<2;b++) acc[a][b] = (float4v){0.f,0.f,0.f,0.f};

  const int srow8 = lane >> 3;
  const int scc   = (lane & 7) ^ srow8;
  const int c3x   = l16 & 7;

  for (int kc = 0; kc < K; kc += 192){
    #pragma unroll
    for (int t=0;t<6;t++){
      int ig = wv*6 + t;
      int g = ig >> 3, ro = ig & 7;
      int row = ro*8 + srow8;
      gload_lds16(A  + (size_t)(m0+row)*K + kc + g*64 + scc*8, As + g*4096 + ro*512);
      gload_lds16(BT + (size_t)(n0+row)*K + kc + g*64 + scc*8, Bs + g*4096 + ro*512);
    }
    __syncthreads();
    #pragma unroll
    for (int ks=0; ks<6; ks++){
      const int cc = ks*4 + quad, g = cc >> 3, c3 = (cc & 7) ^ c3x;
      short8 af[2], bf2[2];
      #pragma unroll
      for (int mt=0;mt<2;mt++) af[mt]  = *(const short8*)(As + g*4096 + (wm+mt*16+l16)*64 + c3*8);
      #pragma unroll
      for (int nt=0;nt<2;nt++) bf2[nt] = *(const short8*)(Bs + g*4096 + (wn+nt*16+l16)*64 + c3*8);
      #pragma unroll
      for (int mt=0;mt<2;mt++)
        #pragma unroll
        for (int nt=0;nt<2;nt++)
          acc[mt][nt] = __builtin_amdgcn_mfma_f32_16x16x32_bf16(af[mt], bf2[nt], acc[mt][nt], 0,0,0);
    }
    if (kc + 192 < K) __syncthreads();
  }

  #pragma unroll
  for (int nt=0;nt<2;nt++){
    int col = n0 + wn + nt*16 + l16;
    float bv = bias[col];
    #pragma unroll
    for (int mt=0;mt<2;mt++){
      float4v a = acc[mt][nt];
      #pragma unroll
      for (int r=0;r<4;r++){
        int mrow = m0 + wm + mt*16 + quad*4 + r;
        float v = a[r] + bv;
        if (MODE == 4){
          if (col < 192) v *= 0.17677669529663687f;
          outb[(size_t)mrow*N + col] = f2b(v);
        } else {
          int win = mrow >> 6, n = mrow & 63;
          int b = win >> 9, rw = win & 511;
          int hs = ((rw>>6)&7)*4 + (n>>4);
          int ws = ((rw>>3)&7)*4 + ((n>>2)&3);
          int ds = (rw&7)*4 + (n&3);
          int h=(hs+2)&31, w=(ws+2)&31, d=(ds+2)&31;
          size_t t = (size_t)((b*32+h)*32+w)*32 + d;
          outf[t*192 + col] = v + resf[t*192 + col];
        }
      }
    }
  }
}

// ---------------- fused LN2 + MLP: 64 tokens/block, 256 threads, 48 KB LDS ----------------
// Round-13: weight-amortization. Round-1 schedule (UP -> GELU -> sync -> DOWN per
// quarter, 2 barriers/quarter) kept intact; the single change is 64 tokens per block
// with 4 waves x 4 token-tiles per wave. Each weight fragment (af) now feeds 4 MFMAs
// instead of 2 -> w1P/w2P L2 traffic halves (1.2 GB -> 0.6 GB) and per-wave MFMA ILP
// doubles (12 independent MFMAs/ks hide L2/LDS latency within-wave). Unlike round-8's
// 8-wave variant, no wave-pair duplicates weight reads. Grid 2048 -> 1024.
__global__ __launch_bounds__(256) void mlp_fused(
    const float* __restrict__ xo, const float* __restrict__ g2, const float* __restrict__ b2,
    const u16* __restrict__ w1P, const float* __restrict__ bm1,
    const u16* __restrict__ w2P, const float* __restrict__ bm2,
    float* __restrict__ out)
{
  __shared__ u16 S[2*64*192];          // 48 KB: Ash(24K) + Hsh(24K)
  u16* Ash = S;                        // 3 k-groups x 64 tok x 64
  u16* Hsh = S + 12288;                // 64 tok x 192 hidden quarter
  const int tid = threadIdx.x;
  const int wv = tid >> 6, lane = tid & 63;
  const int quad = lane >> 4, l16 = lane & 15;
  const int tok0 = blockIdx.x * 64;
  const int c3x = l16 & 7;

  // ---- LN2 in-block: wave wv handles tokens wv*16..wv*16+15, into swizzled Ash ----
  {
    float gg[3], bb[3];
    #pragma unroll
    for (int t=0;t<3;t++){ gg[t] = g2[lane+t*64]; bb[t] = b2[lane+t*64]; }
    for (int tt=0;tt<16;tt++){
      const int tl = wv*16 + tt;
      const float* row = xo + (size_t)(tok0+tl)*192;
      float v[3];
      #pragma unroll
      for (int t=0;t<3;t++) v[t] = row[lane + t*64];
      float s = v[0]+v[1]+v[2];
      float s2 = v[0]*v[0]+v[1]*v[1]+v[2]*v[2];
      #pragma unroll
      for (int o=32;o>=1;o>>=1){ s += __shfl_xor(s,o); s2 += __shfl_xor(s2,o); }
      float mean = s*(1.0f/192.0f);
      float rstd = rsqrtf(s2*(1.0f/192.0f) - mean*mean + 1e-5f);
      const int slot = ((lane>>3) ^ (tl&7));
      #pragma unroll
      for (int t=0;t<3;t++)
        Ash[t*4096 + tl*64 + slot*8 + (lane&7)] = f2b((v[t]-mean)*rstd*gg[t] + bb[t]);
    }
  }
  __syncthreads();

  const int mb = wv*3;           // hc/oc tile base (3 tiles per wave, 12 total)
  float4v dacc[3][4];
  #pragma unroll
  for (int a=0;a<3;a++)
    #pragma unroll
    for (int b=0;b<4;b++) dacc[a][b] = (float4v){0.f,0.f,0.f,0.f};

  for (int p=0; p<4; p++){
    if (p) __syncthreads();      // prev DOWN done reading Hsh
    // ---- UP(p): Ash x w1P(p) -> acc[3][4] ----
    float4v acc[3][4];
    #pragma unroll
    for (int a=0;a<3;a++)
      #pragma unroll
      for (int b=0;b<4;b++) acc[a][b] = (float4v){0.f,0.f,0.f,0.f};
    #pragma unroll
    for (int ks=0; ks<6; ks++){
      const int cc = ks*4 + quad, g = cc >> 3, c3 = (cc & 7) ^ c3x;
      short8 bfU[4], afU[3];
      #pragma unroll
      for (int ntl=0;ntl<4;ntl++)
        bfU[ntl] = *(const short8*)(Ash + g*4096 + (ntl*16+l16)*64 + c3*8);
      #pragma unroll
      for (int mtl=0;mtl<3;mtl++)
        afU[mtl] = *(const short8*)(w1P + ((size_t)((p*12 + mb + mtl)*6 + ks)*64 + lane)*8);
      #pragma unroll
      for (int mtl=0;mtl<3;mtl++)
        #pragma unroll
        for (int ntl=0;ntl<4;ntl++)
          acc[mtl][ntl] = __builtin_amdgcn_mfma_f32_16x16x32_bf16(afU[mtl], bfU[ntl], acc[mtl][ntl], 0,0,0);
    }
    // ---- GELU(p): acc + bm1(p) -> Hsh ----
    #pragma unroll
    for (int mtl=0;mtl<3;mtl++){
      const int hl0 = (mb+mtl)*16 + quad*4;        // local hc 0..191
      const float4v bv = *(const float4v*)(bm1 + p*192 + hl0);
      const int g = hl0 >> 3, sub = hl0 & 7;       // sub in {0,4}
      #pragma unroll
      for (int ntl=0;ntl<4;ntl++){
        const int tok = ntl*16 + l16;
        union { unsigned long long d; u32 w[2]; } pk;
        pk.w[0] = cvtpk_bf16(gelu_t(acc[mtl][ntl][0] + bv[0]), gelu_t(acc[mtl][ntl][1] + bv[1]));
        pk.w[1] = cvtpk_bf16(gelu_t(acc[mtl][ntl][2] + bv[2]), gelu_t(acc[mtl][ntl][3] + bv[3]));
        *(unsigned long long*)(Hsh + tok*192 + ((g ^ (tok&7))<<3) + sub) = pk.d;
      }
    }
    __syncthreads();
    // ---- DOWN(p): Hsh x w2P(p) -> dacc ----
    #pragma unroll
    for (int ks=0; ks<6; ks++){
      const int gd = ks*4 + quad;                  // 0..23
      short8 bfD[4], afD[3];
      #pragma unroll
      for (int ntl=0;ntl<4;ntl++){
        const int tok = ntl*16 + l16;
        bfD[ntl] = *(const short8*)(Hsh + tok*192 + ((gd ^ (tok&7))<<3));
      }
      #pragma unroll
      for (int mtl=0;mtl<3;mtl++)
        afD[mtl] = *(const short8*)(w2P + ((size_t)((mb + mtl)*24 + p*6 + ks)*64 + lane)*8);
      #pragma unroll
      for (int mtl=0;mtl<3;mtl++)
        #pragma unroll
        for (int ntl=0;ntl<4;ntl++)
          dacc[mtl][ntl] = __builtin_amdgcn_mfma_f32_16x16x32_bf16(afD[mtl], bfD[ntl], dacc[mtl][ntl], 0,0,0);
    }
  }
  __syncthreads();   // F-stage (48 KB) overlays Hsh; other waves may be in DOWN(3) reads

  // ---- epilogue: dacc+bias -> fp32 stage in S (swizzled float4), then coalesced out ----
  float4v* F = (float4v*)S;                        // 64*48 = 3072 float4 = 48 KB
  #pragma unroll
  for (int mtl=0;mtl<3;mtl++){
    const int oc0 = (mb+mtl)*16 + quad*4;
    const float4v bv = *(const float4v*)(bm2 + oc0);
    #pragma unroll
    for (int ntl=0;ntl<4;ntl++){
      const int tok = ntl*16 + l16;
      float4v o;
      #pragma unroll
      for (int r=0;r<4;r++) o[r] = dacc[mtl][ntl][r] + bv[r];
      F[tok*48 + ((oc0>>2) ^ (tok&7))] = o;
    }
  }
  __syncthreads();
  const float4v* xo4 = (const float4v*)(xo + (size_t)tok0*192);
  float4v* out4 = (float4v*)(out + (size_t)tok0*192);
  #pragma unroll
  for (int it=0; it<12; it++){
    int f = it*256 + tid;
    int tok = f/48, c = f - tok*48;
    float4v v = F[tok*48 + (c ^ (tok&7))];
    float4v xv = xo4[f];
    #pragma unroll
    for (int r=0;r<4;r++) v[r] += xv[r];
    out4[f] = v;
  }
}

// ---------------- MFMA windowed attention (unchanged) ----------------
__global__ __launch_bounds__(192,3) void attn_mfma(
    const u16* __restrict__ qkv, const float* __restrict__ bias_table,
    u16* __restrict__ out)
{
  __shared__ u16  Psh [3][64*72];
  __shared__ u16  VTsh[3][32*72];
  __shared__ float bsh[3][344];
  const int win  = blockIdx.x >> 1;
  const int wv   = threadIdx.x / 64;
  const int lane = threadIdx.x & 63;
  const int hg   = (blockIdx.x & 1)*3 + wv;
  const int quad = lane >> 4, l16 = lane & 15;

  u16* P  = &Psh[wv][0];
  u16* VT = &VTsh[wv][0];
  float* bs = &bsh[wv][0];
  const u16* base = qkv + (size_t)win*64*576 + hg*32;

  for (int idx = lane; idx < 343; idx += 64) bs[idx] = bias_table[idx*6 + hg];

  {
    const int a = (lane & 15)*4 + (lane >> 4);
    #pragma unroll
    for (int t=0;t<4;t++){
      union { uint4 v; u16 u[8]; } vv;
      vv.v = *(const uint4*)(base + (size_t)lane*576 + 384 + t*8);
      #pragma unroll
      for (int e=0;e<8;e++) VT[(t*8+e)*72 + a] = vv.u[e];
    }
  }

  short8 qf[4], kf[4];
  #pragma unroll
  for (int mt=0;mt<4;mt++) qf[mt] = *(const short8*)(base + (size_t)(mt*16 + l16)*576 + quad*8);
  #pragma unroll
  for (int nt=0;nt<4;nt++) kf[nt] = *(const short8*)(base + (size_t)(nt*16 + l16)*576 + 192 + quad*8);

  float4v s[4][4];
  #pragma unroll
  for (int mt=0;mt<4;mt++)
    #pragma unroll
    for (int nt=0;nt<4;nt++)
      s[mt][nt] = __builtin_amdgcn_mfma_f32_16x16x32_bf16(qf[mt], kf[nt], (float4v){0.f,0.f,0.f,0.f}, 0,0,0);

  const int rwn = win & 511;
  const int bh=(rwn>>6)&7, bw=(rwn>>3)&7, bd=rwn&7;
  const int jw = l16>>2, jd = l16&3;
  const int gw_j = (bw==7) ? ((jw  <2)?3:6) : 0;
  const int gd_j = (bd==7) ? ((jd  <2)?1:2) : 0;
  const int gw_i = (bw==7) ? ((quad<2)?3:6) : 0;
  const int laneoff = (quad - jw)*7 - jd + 171;
  #pragma unroll
  for (int mt=0;mt<4;mt++){
    const int gh_i = (bh==7) ? ((mt<2)?9:18) : 0;
    #pragma unroll
    for (int nt=0;nt<4;nt++){
      const int gh_j = (bh==7) ? ((nt<2)?9:18) : 0;
      const int bb = (mt-nt)*49 + laneoff;
      #pragma unroll
      for (int r=0;r<4;r++){
        const int gd_i = (bd==7) ? ((r<2)?1:2) : 0;
        float sv = s[mt][nt][r] + bs[bb + r];
        if ((gh_i + gw_i + gd_i) != (gh_j + gw_j + gd_j)) sv -= 100.f;
        s[mt][nt][r] = sv;
      }
    }
  }

  #pragma unroll
  for (int mt=0;mt<4;mt++){
    #pragma unroll
    for (int r=0;r<4;r++){
      float m0 = fmaxf(fmaxf(s[mt][0][r], s[mt][1][r]), fmaxf(s[mt][2][r], s[mt][3][r]));
      #pragma unroll
      for (int o=8;o>=1;o>>=1) m0 = fmaxf(m0, __shfl_xor(m0,o));
      float sum = 0.f;
      float e[4];
      #pragma unroll
      for (int nt=0;nt<4;nt++){ e[nt] = __expf(s[mt][nt][r] - m0); sum += e[nt]; }
      #pragma unroll
      for (int o=8;o>=1;o>>=1) sum += __shfl_xor(sum,o);
      const float rinv = __builtin_amdgcn_rcpf(sum);
      union { unsigned long long d; u32 w[2]; } pk;
      pk.w[0] = cvtpk_bf16(e[0]*rinv, e[1]*rinv);
      pk.w[1] = cvtpk_bf16(e[2]*rinv, e[3]*rinv);
      *(unsigned long long*)(&P[(mt*16 + quad*4 + r)*72 + l16*4]) = pk.d;
    }
  }

  float4v o2[4][2];
  #pragma unroll
  for (int mt=0;mt<4;mt++){ o2[mt][0]=(float4v){0.f,0.f,0.f,0.f}; o2[mt][1]=(float4v){0.f,0.f,0.f,0.f}; }
  #pragma unroll
  for (int s2=0;s2<2;s2++){
    short8 vfrag[2];
    #pragma unroll
    for (int ct=0;ct<2;ct++) vfrag[ct] = *(const short8*)(&VT[(ct*16 + l16)*72 + s2*32 + quad*8]);
    #pragma unroll
    for (int mt=0;mt<4;mt++){
      short8 pfrag = *(const short8*)(&P[(mt*16 + l16)*72 + s2*32 + quad*8]);
      #pragma unroll
      for (int ct=0;ct<2;ct++)
        o2[mt][ct] = __builtin_amdgcn_mfma_f32_16x16x32_bf16(pfrag, vfrag[ct], o2[mt][ct], 0,0,0);
    }
  }

  #pragma unroll
  for (int mt=0;mt<4;mt++)
    #pragma unroll
    for (int ct=0;ct<2;ct++)
      #pragma unroll
      for (int r=0;r<4;r++){
        int i = mt*16 + quad*4 + r;
        out[((size_t)win*64 + i)*192 + hg*32 + ct*16 + l16] = f2b(o2[mt][ct][r]);
      }
}

// ---------------- driver ----------------
extern "C" void kernel_launch(void* const* d_in, const int* in_sizes, int n_in,
                              void* d_out, int out_size, void* d_ws, size_t ws_size,
                              hipStream_t stream)
{
  const float* x    = (const float*)d_in[0];
  const float* g1   = (const float*)d_in[1];
  const float* b1   = (const float*)d_in[2];
  const float* wqkv = (const float*)d_in[3];
  const float* bqkv = (const float*)d_in[4];
  const float* wo   = (const float*)d_in[5];
  const float* bo   = (const float*)d_in[6];
  const float* btab = (const float*)d_in[7];
  const float* g2   = (const float*)d_in[8];
  const float* b2v  = (const float*)d_in[9];
  const float* w1   = (const float*)d_in[10];
  const float* bm1  = (const float*)d_in[11];
  const float* w2   = (const float*)d_in[12];
  const float* bm2  = (const float*)d_in[13];
  float* out = (float*)d_out;

  char* ws = (char*)d_ws;
  u16*  wqkvT = (u16*)(ws + 0);            // [576][192]
  u16*  woT   = (u16*)(ws + 221184);       // [192][192]
  u16*  w1P   = (u16*)(ws + 294912);       // packed 48x6x512
  u16*  w2P   = (u16*)(ws + 589824);       // packed 12x24x512
  u16*  xw    = (u16*)(ws + 1048576);      // 65536x192 bf16
  u16*  qkvb  = (u16*)(ws + 26214400);     // 65536x576 bf16 (dead after attn)
  float* xo   = (float*)(ws + 26214400);   // 65536x192 fp32 (overlays dead qkv)

  transpose_all<<<1728,256,0,stream>>>(wqkv, wo, w1, w2, wqkvT, woT, w1P, w2P);

  // LN1 + shift + window partition  (fp32 x -> bf16 xw)
  ln_kernel<<<16384,256,0,stream>>>(x, g1, b1, xw);
  // QKV projection (+ q-scale): [65536,192] @ [192,576], XCD-swizzled
  gemm_fk<4,9><<<9216,256,0,stream>>>(xw, wqkvT, bqkv, 192, 576, qkvb, nullptr, nullptr);
  // MFMA windowed attention (writes attn_out over xw)
  attn_mfma<<<2048,192,0,stream>>>(qkvb, btab, xw);
  // output projection + window-reverse + unshift + fp32 x residual -> xo (fp32)
  gemm_fk<2,3><<<3072,256,0,stream>>>(xw, woT, bo, 192, 192, nullptr, xo, x);
  // fused LN2 + MLP: out = xo + gelu(ln(xo)@w1+bm1)@w2 + bm2 (64 tok/block)
  mlp_fused<<<1024,256,0,stream>>>(xo, g2, b2v, w1P, bm1, w2P, bm2, out);
}

// Round 12
// 273.061 us; speedup vs baseline: 1.0829x; 1.0829x over previous
//
#include <hip/hip_runtime.h>
#include <math.h>

typedef unsigned short u16;
typedef unsigned int   u32;
using short8  = __attribute__((ext_vector_type(8))) short;
using float4v = __attribute__((ext_vector_type(4))) float;

__device__ __forceinline__ float b2f(u16 u){ return __uint_as_float(((u32)u)<<16); }
__device__ __forceinline__ u16 f2b(float f){
  u32 x = __float_as_uint(f);
  x += 0x7FFFu + ((x>>16)&1u);   // RNE; inputs are tame (no NaN)
  return (u16)(x>>16);
}

// hardware packed f32->bf16 (RNE), 1 instr for 2 values
__device__ __forceinline__ u32 cvtpk_bf16(float lo, float hi){
  u32 r; asm("v_cvt_pk_bf16_f32 %0, %1, %2" : "=v"(r) : "v"(lo), "v"(hi));
  return r;
}

// async global->LDS, 16B per lane. LDS dest = wave-uniform base + lane*16.
__device__ __forceinline__ void gload_lds16(const u16* g, u16* l){
  __builtin_amdgcn_global_load_lds((const __attribute__((address_space(1))) void*)g,
                                   (__attribute__((address_space(3))) void*)l, 16, 0, 0);
}

// tanh-form GELU in sigmoid shape: x * rcp(1 + exp2(x*fma(c2,x^2,c1)))
// 7 VALU instrs (2 transcendental), no fp32 divide. |err vs exact erf-GELU| <~3e-3.
__device__ __forceinline__ float gelu_t(float x){
  float x2 = x*x;
  float z  = x * __builtin_fmaf(-0.1029434f, x2, -2.3022077f);
  float e  = __builtin_amdgcn_exp2f(z);
  return x * __builtin_amdgcn_rcpf(1.f + e);
}

// ------- weight prep: wqkvT/woT transposed; w1P/w2P packed; btabT bias transpose -------
__global__ void transpose_all(const float* __restrict__ wqkv, const float* __restrict__ wo,
                              const float* __restrict__ w1,   const float* __restrict__ w2,
                              const float* __restrict__ btab,
                              u16* __restrict__ wqkvT, u16* __restrict__ woT,
                              u16* __restrict__ w1P,   u16* __restrict__ w2P,
                              float* __restrict__ btabT){
  int idx = blockIdx.x*256 + threadIdx.x;
  if (idx < 110592){ int r=idx/576, c=idx-r*576; wqkvT[c*192+r]=f2b(wqkv[idx]); }
  else if (idx < 147456){ int j=idx-110592; int r=j/192, c=j-r*192; woT[c*192+r]=f2b(wo[j]); }
  else if (idx < 294912){
    int j = idx-147456;
    int tile = j >> 9, w = j & 511;            // tile = hct*6+ks
    int e = w & 7, l16 = (w>>3)&15, quad = w>>7;
    int hc = (tile/6)*16 + l16, k = (tile%6)*32 + quad*8 + e;
    w1P[j] = f2b(w1[k*768 + hc]);
  } else if (idx < 442368){
    int j = idx-294912;
    int tile = j >> 9, w = j & 511;            // tile = oct*24+kk
    int e = w & 7, l16 = (w>>3)&15, quad = w>>7;
    int oc = (tile/24)*16 + l16, k = (tile%24)*32 + quad*8 + e;
    w2P[j] = f2b(w2[k*192 + oc]);
  } else if (idx < 444426){
    int j = idx-442368;                        // bias_table [343][6] -> btabT [6][343]
    btabT[(j%6)*343 + j/6] = btab[j];
  }
}

// ---------------- LayerNorm1 (fp32 in, bf16 out) + roll(-2) + window partition ----------------
__global__ __launch_bounds__(256) void ln_kernel(const float* __restrict__ x,
    const float* __restrict__ g, const float* __restrict__ bvec,
    u16* __restrict__ out)
{
  int wave = threadIdx.x >> 6, lane = threadIdx.x & 63;
  int token = blockIdx.x*4 + wave;          // enumerates SHIFTED coords
  int b = token >> 15, r = token & 32767;
  int hs = r >> 10, ws = (r >> 5) & 31, ds = r & 31;
  int h = (hs+2)&31, w = (ws+2)&31, d = (ds+2)&31;
  int src = ((b*32 + h)*32 + w)*32 + d;
  int win = ((b*8 + (hs>>2))*8 + (ws>>2))*8 + (ds>>2);
  int n   = ((hs&3)*4 + (ws&3))*4 + (ds&3);
  int dst = win*64 + n;
  float v[3];
  #pragma unroll
  for (int t=0;t<3;t++) v[t] = x[(size_t)src*192 + lane + t*64];
  float s  = v[0]+v[1]+v[2];
  float s2 = v[0]*v[0]+v[1]*v[1]+v[2]*v[2];
  #pragma unroll
  for (int o=32;o>=1;o>>=1){ s += __shfl_xor(s,o); s2 += __shfl_xor(s2,o); }
  float mean = s*(1.0f/192.0f);
  float var  = s2*(1.0f/192.0f) - mean*mean;
  float rstd = rsqrtf(var + 1e-5f);
  #pragma unroll
  for (int t=0;t<3;t++){
    int c = lane + t*64;
    out[(size_t)dst*192 + c] = f2b((v[t]-mean)*rstd*g[c] + bvec[c]);
  }
}

// ---------------- MFMA GEMM, full-K-chunk, XCD-swizzled grid ----------------
// MODE 4 (QKV): writes qkvb in head-major layout [win][head][sel][n][32] so that
// attn_mfma's Q/K/V reads are COALESCED (old row-major [tok][576] made every attn
// fragment load a 64-line gather at stride 1152B).
template<int MODE, int NB>
__global__ __launch_bounds__(256) void gemm_fk(
    const u16* __restrict__ A, const u16* __restrict__ BT, const float* __restrict__ bias,
    const int K, const int N,
    u16* __restrict__ outb, float* __restrict__ outf, const float* __restrict__ resf)
{
  __shared__ u16 As[64*192];
  __shared__ u16 Bs[64*192];
  const int lin = blockIdx.x;
  const int xcd = lin & 7, idx = lin >> 3;
  const int mb = idx / NB, nb = idx - mb*NB;
  const int m0 = (xcd*128 + mb) * 64, n0 = nb * 64;
  const int tid = threadIdx.x;
  const int wv = tid >> 6, lane = tid & 63;
  const int quad = lane >> 4, l16 = lane & 15;
  const int wm = (wv >> 1) * 32, wn = (wv & 1) * 32;

  float4v acc[2][2];
  #pragma unroll
  for (int a=0;a<2;a++) for (int b=0;b<2;b++) acc[a][b] = (float4v){0.f,0.f,0.f,0.f};

  const int srow8 = lane >> 3;
  const int scc   = (lane & 7) ^ srow8;
  const int c3x   = l16 & 7;

  for (int kc = 0; kc < K; kc += 192){
    #pragma unroll
    for (int t=0;t<6;t++){
      int ig = wv*6 + t;
      int g = ig >> 3, ro = ig & 7;
      int row = ro*8 + srow8;
      gload_lds16(A  + (size_t)(m0+row)*K + kc + g*64 + scc*8, As + g*4096 + ro*512);
      gload_lds16(BT + (size_t)(n0+row)*K + kc + g*64 + scc*8, Bs + g*4096 + ro*512);
    }
    __syncthreads();
    #pragma unroll
    for (int ks=0; ks<6; ks++){
      const int cc = ks*4 + quad, g = cc >> 3, c3 = (cc & 7) ^ c3x;
      short8 af[2], bf2[2];
      #pragma unroll
      for (int mt=0;mt<2;mt++) af[mt]  = *(const short8*)(As + g*4096 + (wm+mt*16+l16)*64 + c3*8);
      #pragma unroll
      for (int nt=0;nt<2;nt++) bf2[nt] = *(const short8*)(Bs + g*4096 + (wn+nt*16+l16)*64 + c3*8);
      #pragma unroll
      for (int mt=0;mt<2;mt++)
        #pragma unroll
        for (int nt=0;nt<2;nt++)
          acc[mt][nt] = __builtin_amdgcn_mfma_f32_16x16x32_bf16(af[mt], bf2[nt], acc[mt][nt], 0,0,0);
    }
    if (kc + 192 < K) __syncthreads();
  }

  #pragma unroll
  for (int nt=0;nt<2;nt++){
    int cb  = n0 + wn + nt*16;          // 16-aligned column base, uniform per nt
    int col = cb + l16;
    float bv = bias[col];
    // MODE 4 head-major decomposition (uniform per nt: 16-col tile never crosses a 32 boundary)
    int sel  = cb / 192;
    int rem  = cb - sel*192;
    int hh   = rem >> 5, hd0 = rem & 31;
    #pragma unroll
    for (int mt=0;mt<2;mt++){
      float4v a = acc[mt][nt];
      #pragma unroll
      for (int r=0;r<4;r++){
        int mrow = m0 + wm + mt*16 + quad*4 + r;
        float v = a[r] + bv;
        if (MODE == 4){
          if (sel == 0) v *= 0.17677669529663687f;
          int win = mrow >> 6, n = mrow & 63;
          size_t dst = ((size_t)(win*6 + hh)*3 + sel)*2048 + n*32 + hd0 + l16;
          outb[dst] = f2b(v);
        } else {
          int win = mrow >> 6, n = mrow & 63;
          int b = win >> 9, rw = win & 511;
          int hs = ((rw>>6)&7)*4 + (n>>4);
          int ws = ((rw>>3)&7)*4 + ((n>>2)&3);
          int ds = (rw&7)*4 + (n&3);
          int h=(hs+2)&31, w=(ws+2)&31, d=(ds+2)&31;
          size_t t = (size_t)((b*32+h)*32+w)*32 + d;
          outf[t*192 + col] = v + resf[t*192 + col];
        }
      }
    }
  }
}

// ---------------- fused LN2 + MLP: 32 tokens/block, 256 threads, 24 KB LDS ----------------
// Round-1 form EXACT (proven 84.4 us). r2/r7/r11 restructures all lost by trading
// occupancy for schedule changes -- this kernel is latency-bound and wants waves.
__global__ __launch_bounds__(256) void mlp_fused(
    const float* __restrict__ xo, const float* __restrict__ g2, const float* __restrict__ b2,
    const u16* __restrict__ w1P, const float* __restrict__ bm1,
    const u16* __restrict__ w2P, const float* __restrict__ bm2,
    float* __restrict__ out)
{
  __shared__ u16 S[2*32*192];          // 24 KB
  u16* Ash = S;                        // 32 tok x 192 (3 k-groups of 64)
  u16* Hsh = S + 32*192;               // 32 tok x 192 hidden quarter
  const int tid = threadIdx.x;
  const int wv = tid >> 6, lane = tid & 63;
  const int quad = lane >> 4, l16 = lane & 15;
  const int tok0 = blockIdx.x * 32;
  const int c3x = l16 & 7;

  // ---- LN2 in-block: wave wv handles tokens wv*8..wv*8+7, into swizzled Ash ----
  {
    float gg[3], bb[3];
    #pragma unroll
    for (int t=0;t<3;t++){ gg[t] = g2[lane+t*64]; bb[t] = b2[lane+t*64]; }
    #pragma unroll
    for (int tt=0;tt<8;tt++){
      const int tl = wv*8 + tt;
      const float* row = xo + (size_t)(tok0+tl)*192;
      float v[3];
      #pragma unroll
      for (int t=0;t<3;t++) v[t] = row[lane + t*64];
      float s = v[0]+v[1]+v[2];
      float s2 = v[0]*v[0]+v[1]*v[1]+v[2]*v[2];
      #pragma unroll
      for (int o=32;o>=1;o>>=1){ s += __shfl_xor(s,o); s2 += __shfl_xor(s2,o); }
      float mean = s*(1.0f/192.0f);
      float rstd = rsqrtf(s2*(1.0f/192.0f) - mean*mean + 1e-5f);
      const int slot = ((lane>>3) ^ (tl&7));
      #pragma unroll
      for (int t=0;t<3;t++)
        Ash[t*2048 + tl*64 + slot*8 + (lane&7)] = f2b((v[t]-mean)*rstd*gg[t] + bb[t]);
    }
  }
  __syncthreads();

  const int mb = wv*3;           // hc/oc tile base (3 tiles per wave, 12 total)
  float4v dacc[3][2];
  #pragma unroll
  for (int a=0;a<3;a++) for (int b=0;b<2;b++) dacc[a][b] = (float4v){0.f,0.f,0.f,0.f};

  for (int p=0; p<4; p++){
    if (p) __syncthreads();      // prev DOWN done reading Hsh
    // ---- UP quarter: h[p*192 .. +192) ----
    float4v acc[3][2];
    #pragma unroll
    for (int a=0;a<3;a++) for (int b=0;b<2;b++) acc[a][b] = (float4v){0.f,0.f,0.f,0.f};
    #pragma unroll
    for (int ks=0; ks<6; ks++){
      const int cc = ks*4 + quad, g = cc >> 3, c3 = (cc & 7) ^ c3x;
      short8 bf[2], af[3];
      #pragma unroll
      for (int ntl=0;ntl<2;ntl++)
        bf[ntl] = *(const short8*)(Ash + g*2048 + (ntl*16+l16)*64 + c3*8);
      #pragma unroll
      for (int mtl=0;mtl<3;mtl++)
        af[mtl] = *(const short8*)(w1P + ((size_t)((p*12 + mb + mtl)*6 + ks)*64 + lane)*8);
      #pragma unroll
      for (int mtl=0;mtl<3;mtl++)
        #pragma unroll
        for (int ntl=0;ntl<2;ntl++)
          acc[mtl][ntl] = __builtin_amdgcn_mfma_f32_16x16x32_bf16(af[mtl], bf[ntl], acc[mtl][ntl], 0,0,0);
    }
    // bias + GELU -> swizzled Hsh (row stride 192 u16)
    #pragma unroll
    for (int mtl=0;mtl<3;mtl++){
      const int hl0 = (mb+mtl)*16 + quad*4;        // local hc 0..191
      const float4v bv = *(const float4v*)(bm1 + p*192 + hl0);
      const int g = hl0 >> 3, sub = hl0 & 7;       // sub in {0,4}
      #pragma unroll
      for (int ntl=0;ntl<2;ntl++){
        const int tok = ntl*16 + l16;
        union { unsigned long long d; u32 w[2]; } pk;
        pk.w[0] = cvtpk_bf16(gelu_t(acc[mtl][ntl][0] + bv[0]), gelu_t(acc[mtl][ntl][1] + bv[1]));
        pk.w[1] = cvtpk_bf16(gelu_t(acc[mtl][ntl][2] + bv[2]), gelu_t(acc[mtl][ntl][3] + bv[3]));
        *(unsigned long long*)(Hsh + tok*192 + ((g ^ (tok&7))<<3) + sub) = pk.d;
      }
    }
    __syncthreads();
    // ---- DOWN quarter: accumulate ----
    #pragma unroll
    for (int ks=0; ks<6; ks++){
      const int g = ks*4 + quad;                   // 0..23
      short8 bf[2], af[3];
      #pragma unroll
      for (int ntl=0;ntl<2;ntl++){
        const int tok = ntl*16 + l16;
        bf[ntl] = *(const short8*)(Hsh + tok*192 + ((g ^ (tok&7))<<3));
      }
      #pragma unroll
      for (int mtl=0;mtl<3;mtl++)
        af[mtl] = *(const short8*)(w2P + ((size_t)((mb+mtl)*24 + p*6 + ks)*64 + lane)*8);
      #pragma unroll
      for (int mtl=0;mtl<3;mtl++)
        #pragma unroll
        for (int ntl=0;ntl<2;ntl++)
          dacc[mtl][ntl] = __builtin_amdgcn_mfma_f32_16x16x32_bf16(af[mtl], bf[ntl], dacc[mtl][ntl], 0,0,0);
    }
  }
  __syncthreads();

  // ---- epilogue: dacc+bias -> fp32 stage in S (swizzled float4), then coalesced out ----
  float4v* F = (float4v*)S;                        // 1536 float4 = 24 KB
  #pragma unroll
  for (int mtl=0;mtl<3;mtl++){
    const int oc0 = (mb+mtl)*16 + quad*4;
    const float4v bv = *(const float4v*)(bm2 + oc0);
    #pragma unroll
    for (int ntl=0;ntl<2;ntl++){
      const int tok = ntl*16 + l16;
      float4v o;
      #pragma unroll
      for (int r=0;r<4;r++) o[r] = dacc[mtl][ntl][r] + bv[r];
      F[tok*48 + ((oc0>>2) ^ (tok&7))] = o;
    }
  }
  __syncthreads();
  const float4v* xo4 = (const float4v*)(xo + (size_t)tok0*192);
  float4v* out4 = (float4v*)(out + (size_t)tok0*192);
  #pragma unroll
  for (int it=0; it<6; it++){
    int f = it*256 + tid;
    int tok = f/48, c = f - tok*48;
    float4v v = F[tok*48 + (c ^ (tok&7))];
    float4v xv = xo4[f];
    #pragma unroll
    for (int r=0;r<4;r++) v[r] += xv[r];
    out4[f] = v;
  }
}

// ---------------- MFMA windowed attention (head-major qkv: coalesced reads) ----------------
__global__ __launch_bounds__(192,3) void attn_mfma(
    const u16* __restrict__ qkv, const float* __restrict__ btabT,
    u16* __restrict__ out)
{
  __shared__ u16  Psh [3][64*72];
  __shared__ u16  VTsh[3][32*72];
  __shared__ float bsh[3][344];
  const int win  = blockIdx.x >> 1;
  const int wv   = threadIdx.x / 64;
  const int lane = threadIdx.x & 63;
  const int hg   = (blockIdx.x & 1)*3 + wv;
  const int quad = lane >> 4, l16 = lane & 15;

  u16* P  = &Psh[wv][0];
  u16* VT = &VTsh[wv][0];
  float* bs = &bsh[wv][0];
  // head-major layout: [win][head][sel][n 64][hd 32]
  const u16* base_q = qkv + ((size_t)(win*6 + hg)*3)*2048;

  for (int idx = lane; idx < 343; idx += 64) bs[idx] = btabT[hg*343 + idx];

  {
    const int a = (lane & 15)*4 + (lane >> 4);
    #pragma unroll
    for (int t=0;t<4;t++){
      union { uint4 v; u16 u[8]; } vv;
      vv.v = *(const uint4*)(base_q + 4096 + lane*32 + t*8);   // V[n=lane][hd=t*8..+7]
      #pragma unroll
      for (int e=0;e<8;e++) VT[(t*8+e)*72 + a] = vv.u[e];
    }
  }

  short8 qf[4], kf[4];
  #pragma unroll
  for (int mt=0;mt<4;mt++) qf[mt] = *(const short8*)(base_q + (mt*16 + l16)*32 + quad*8);
  #pragma unroll
  for (int nt=0;nt<4;nt++) kf[nt] = *(const short8*)(base_q + 2048 + (nt*16 + l16)*32 + quad*8);

  float4v s[4][4];
  #pragma unroll
  for (int mt=0;mt<4;mt++)
    #pragma unroll
    for (int nt=0;nt<4;nt++)
      s[mt][nt] = __builtin_amdgcn_mfma_f32_16x16x32_bf16(qf[mt], kf[nt], (float4v){0.f,0.f,0.f,0.f}, 0,0,0);

  const int rwn = win & 511;
  const int bh=(rwn>>6)&7, bw=(rwn>>3)&7, bd=rwn&7;
  const int jw = l16>>2, jd = l16&3;
  const int gw_j = (bw==7) ? ((jw  <2)?3:6) : 0;
  const int gd_j = (bd==7) ? ((jd  <2)?1:2) : 0;
  const int gw_i = (bw==7) ? ((quad<2)?3:6) : 0;
  const int laneoff = (quad - jw)*7 - jd + 171;
  #pragma unroll
  for (int mt=0;mt<4;mt++){
    const int gh_i = (bh==7) ? ((mt<2)?9:18) : 0;
    #pragma unroll
    for (int nt=0;nt<4;nt++){
      const int gh_j = (bh==7) ? ((nt<2)?9:18) : 0;
      const int bb = (mt-nt)*49 + laneoff;
      #pragma unroll
      for (int r=0;r<4;r++){
        const int gd_i = (bd==7) ? ((r<2)?1:2) : 0;
        float sv = s[mt][nt][r] + bs[bb + r];
        if ((gh_i + gw_i + gd_i) != (gh_j + gw_j + gd_j)) sv -= 100.f;
        s[mt][nt][r] = sv;
      }
    }
  }

  #pragma unroll
  for (int mt=0;mt<4;mt++){
    #pragma unroll
    for (int r=0;r<4;r++){
      float m0 = fmaxf(fmaxf(s[mt][0][r], s[mt][1][r]), fmaxf(s[mt][2][r], s[mt][3][r]));
      #pragma unroll
      for (int o=8;o>=1;o>>=1) m0 = fmaxf(m0, __shfl_xor(m0,o));
      float sum = 0.f;
      float e[4];
      #pragma unroll
      for (int nt=0;nt<4;nt++){ e[nt] = __expf(s[mt][nt][r] - m0); sum += e[nt]; }
      #pragma unroll
      for (int o=8;o>=1;o>>=1) sum += __shfl_xor(sum,o);
      const float rinv = __builtin_amdgcn_rcpf(sum);
      union { unsigned long long d; u32 w[2]; } pk;
      pk.w[0] = cvtpk_bf16(e[0]*rinv, e[1]*rinv);
      pk.w[1] = cvtpk_bf16(e[2]*rinv, e[3]*rinv);
      *(unsigned long long*)(&P[(mt*16 + quad*4 + r)*72 + l16*4]) = pk.d;
    }
  }

  float4v o2[4][2];
  #pragma unroll
  for (int mt=0;mt<4;mt++){ o2[mt][0]=(float4v){0.f,0.f,0.f,0.f}; o2[mt][1]=(float4v){0.f,0.f,0.f,0.f}; }
  #pragma unroll
  for (int s2=0;s2<2;s2++){
    short8 vfrag[2];
    #pragma unroll
    for (int ct=0;ct<2;ct++) vfrag[ct] = *(const short8*)(&VT[(ct*16 + l16)*72 + s2*32 + quad*8]);
    #pragma unroll
    for (int mt=0;mt<4;mt++){
      short8 pfrag = *(const short8*)(&P[(mt*16 + l16)*72 + s2*32 + quad*8]);
      #pragma unroll
      for (int ct=0;ct<2;ct++)
        o2[mt][ct] = __builtin_amdgcn_mfma_f32_16x16x32_bf16(pfrag, vfrag[ct], o2[mt][ct], 0,0,0);
    }
  }

  #pragma unroll
  for (int mt=0;mt<4;mt++)
    #pragma unroll
    for (int ct=0;ct<2;ct++)
      #pragma unroll
      for (int r=0;r<4;r++){
        int i = mt*16 + quad*4 + r;
        out[((size_t)win*64 + i)*192 + hg*32 + ct*16 + l16] = f2b(o2[mt][ct][r]);
      }
}

// ---------------- driver ----------------
extern "C" void kernel_launch(void* const* d_in, const int* in_sizes, int n_in,
                              void* d_out, int out_size, void* d_ws, size_t ws_size,
                              hipStream_t stream)
{
  const float* x    = (const float*)d_in[0];
  const float* g1   = (const float*)d_in[1];
  const float* b1   = (const float*)d_in[2];
  const float* wqkv = (const float*)d_in[3];
  const float* bqkv = (const float*)d_in[4];
  const float* wo   = (const float*)d_in[5];
  const float* bo   = (const float*)d_in[6];
  const float* btab = (const float*)d_in[7];
  const float* g2   = (const float*)d_in[8];
  const float* b2v  = (const float*)d_in[9];
  const float* w1   = (const float*)d_in[10];
  const float* bm1  = (const float*)d_in[11];
  const float* w2   = (const float*)d_in[12];
  const float* bm2  = (const float*)d_in[13];
  float* out = (float*)d_out;

  char* ws = (char*)d_ws;
  u16*  wqkvT = (u16*)(ws + 0);            // [576][192]
  u16*  woT   = (u16*)(ws + 221184);       // [192][192]
  u16*  w1P   = (u16*)(ws + 294912);       // packed 48x6x512
  u16*  w2P   = (u16*)(ws + 589824);       // packed 12x24x512
  float* btabT= (float*)(ws + 884736);     // [6][343]
  u16*  xw    = (u16*)(ws + 1048576);      // 65536x192 bf16
  u16*  qkvb  = (u16*)(ws + 26214400);     // head-major [1024][6][3][64][32] bf16 (dead after attn)
  float* xo   = (float*)(ws + 26214400);   // 65536x192 fp32 (overlays dead qkv)

  transpose_all<<<1737,256,0,stream>>>(wqkv, wo, w1, w2, btab, wqkvT, woT, w1P, w2P, btabT);

  // LN1 + shift + window partition  (fp32 x -> bf16 xw)
  ln_kernel<<<16384,256,0,stream>>>(x, g1, b1, xw);
  // QKV projection (+ q-scale): [65536,192] @ [192,576], head-major output
  gemm_fk<4,9><<<9216,256,0,stream>>>(xw, wqkvT, bqkv, 192, 576, qkvb, nullptr, nullptr);
  // MFMA windowed attention (coalesced head-major reads; writes attn_out over xw)
  attn_mfma<<<2048,192,0,stream>>>(qkvb, btabT, xw);
  // output projection + window-reverse + unshift + fp32 x residual -> xo (fp32)
  gemm_fk<2,3><<<3072,256,0,stream>>>(xw, woT, bo, 192, 192, nullptr, xo, x);
  // fused LN2 + MLP: out = xo + gelu(ln(xo)@w1+bm1)@w2 + bm2
  mlp_fused<<<2048,256,0,stream>>>(xo, g2, b2v, w1P, bm1, w2P, bm2, out);
}